// Round 13
// baseline (310.498 us; speedup 1.0000x reference)
//
#include <hip/hip_runtime.h>
#include <hip/hip_bf16.h>
#include <math.h>

typedef __hip_bfloat16 bf16;
typedef short bf8_t __attribute__((ext_vector_type(8)));
typedef float f4_t  __attribute__((ext_vector_type(4)));
typedef float f2_t  __attribute__((ext_vector_type(2)));
#define MFMA16(a,b,c) __builtin_amdgcn_mfma_f32_16x16x32_bf16(a,b,c,0,0,0)
#define DEV __device__ __forceinline__

DEV float bf2f(bf16 h){ return __bfloat162float(h); }
DEV bf16 f2bf(float f){ return __float2bfloat16(f); }
DEV float ld(const void* p, size_t i, int md){
  return md ? ((const float*)p)[i] : bf2f(((const bf16*)p)[i]);
}
DEV float wred(float v){
  #pragma unroll
  for(int off=32; off>0; off>>=1) v += __shfl_down(v, off, 64);
  return __shfl(v, 0, 64);
}

// ---------------- K0: detect input dtype (f32 mantissa halves decode huge as bf16)
__global__ __launch_bounds__(256) void k_detect(const unsigned short* __restrict__ xr, int* __restrict__ flag){
  __shared__ float sm[4];
  int t = threadIdx.x;
  float m = 0.f;
  for(int i=t;i<8192;i+=256){
    unsigned int w = ((unsigned int)xr[i]) << 16;
    float v = fabsf(__uint_as_float(w));
    if(v != v) v = 1e30f;
    m = fmaxf(m, v);
  }
  #pragma unroll
  for(int off=32; off>0; off>>=1) m = fmaxf(m, __shfl_down(m, off, 64));
  if((t & 63) == 0) sm[t >> 6] = m;
  __syncthreads();
  if(t == 0){
    float mm = fmaxf(fmaxf(sm[0], sm[1]), fmaxf(sm[2], sm[3]));
    *flag = (mm > 1e10f) ? 1 : 0;
  }
}

// ---------------- K0b: convert GEMM weights to bf16 workspace copies
// layout: [0,16384) inw | [16384,24576) outw | [24576,90112) projw | [90112,155648) pww
__global__ __launch_bounds__(256) void k_wcvt(const void* __restrict__ inw, const void* __restrict__ outw,
                                              const void* __restrict__ projw, const void* __restrict__ pww,
                                              bf16* __restrict__ dst, const int* __restrict__ modep){
  const int md = *modep;
  int g = blockIdx.x*256 + threadIdx.x;
  if(g >= 155648) return;
  const void* src; int i;
  if(g < 16384){ src = inw;   i = g; }
  else if(g < 24576){ src = outw;  i = g - 16384; }
  else if(g < 90112){ src = projw; i = g - 24576; }
  else { src = pww; i = g - 90112; }
  dst[g] = f2bf(ld(src, (size_t)i, md));
}

// ---------------- K1: LayerNorm over C=256 of x[B,C,L] -> xnorm[B,L,256] (bf16)
// Coalesced tile version: LDS-transpose a [256 c][64 l] tile, reduce per row, write lane->c.
__global__ __launch_bounds__(256) void k_ln1(const void* __restrict__ x, const void* __restrict__ gam,
                                             const void* __restrict__ bet, bf16* __restrict__ xnb,
                                             const int* __restrict__ modep){
  __shared__ float sh[64*257];
  __shared__ float mus[64], rss[64];
  const int md = *modep;
  int t = threadIdx.x;
  int b = blockIdx.x >> 6, lt = blockIdx.x & 63;
  int l0 = lt << 6;
  int lane = t & 63, cg = t >> 6;
  size_t xbase = ((size_t)b << 20) + l0 + lane;
  if(md){
    const float* xp = (const float*)x + xbase;
    #pragma unroll 8
    for(int c = cg; c < 256; c += 4)
      sh[lane*257 + c] = xp[(size_t)c << 12];
  } else {
    const bf16* xp = (const bf16*)x + xbase;
    #pragma unroll 8
    for(int c = cg; c < 256; c += 4)
      sh[lane*257 + c] = bf2f(xp[(size_t)c << 12]);
  }
  __syncthreads();
  {
    int row = t >> 2, q = t & 3;
    const float* rp = sh + row*257 + q*64;
    float s = 0.f, s2 = 0.f;
    #pragma unroll 8
    for(int i=0;i<64;i++){ float v = rp[i]; s += v; s2 += v*v; }
    s  += __shfl_xor(s, 1, 64);  s2 += __shfl_xor(s2, 1, 64);
    s  += __shfl_xor(s, 2, 64);  s2 += __shfl_xor(s2, 2, 64);
    if(q == 0){
      float mu = s*(1.f/256.f);
      mus[row] = mu;
      rss[row] = rsqrtf(s2*(1.f/256.f) - mu*mu + 1e-5f);
    }
  }
  __syncthreads();
  int r0 = (t >> 6) << 4;
  #pragma unroll
  for(int k=0;k<4;k++){
    int c = (t & 63) + (k << 6);
    float gv = ld(gam, c, md), bv = ld(bet, c, md);
    #pragma unroll 4
    for(int rr=0; rr<16; rr++){
      int row = r0 + rr;
      xnb[((size_t)(b*4096 + l0 + row))*256 + c] =
        f2bf((sh[row*257 + c] - mus[row])*rss[row]*gv + bv);
    }
  }
}

// ---------------- K2: in_proj MFMA  (M=65536 rows, K=64, N=256 -> xc|z)
__global__ __launch_bounds__(256) void k_inproj(const bf16* __restrict__ xnb, const bf16* __restrict__ wb,
                                                bf16* __restrict__ xcb, bf16* __restrict__ zb){
  __shared__ bf16 As[64*72];
  __shared__ bf16 Ws[256*72];
  int t = threadIdx.x;
  int bm = blockIdx.x >> 6, lt = blockIdx.x & 63;
  int p = bm >> 2, b = bm & 3, l0 = lt << 6;
  #pragma unroll
  for(int pass=0; pass<2; pass++){
    int idx = t + pass*256, r = idx >> 3, ch = idx & 7;
    *(uint4*)&As[r*72 + ch*8] = *(const uint4*)&xnb[((size_t)(b*4096 + l0 + r))*256 + p*64 + ch*8];
  }
  #pragma unroll
  for(int pass=0; pass<8; pass++){
    int idx = t + pass*256, e = idx >> 3, ch = idx & 7;
    *(uint4*)&Ws[e*72 + ch*8] = *(const uint4*)&wb[(size_t)e*64 + ch*8];
  }
  __syncthreads();
  int lane = t & 63, w = t >> 6, quad = lane >> 4, lr = lane & 15;
  f4_t acc[16];
  #pragma unroll
  for(int nt=0;nt<16;nt++) acc[nt] = (f4_t){0.f,0.f,0.f,0.f};
  #pragma unroll
  for(int kk=0; kk<64; kk+=32){
    bf8_t a = *(const bf8_t*)&As[(w*16 + lr)*72 + kk + quad*8];
    #pragma unroll
    for(int nt=0;nt<16;nt++){
      bf8_t bb = *(const bf8_t*)&Ws[(nt*16 + lr)*72 + kk + quad*8];
      acc[nt] = MFMA16(a, bb, acc[nt]);
    }
  }
  __syncthreads();
  bf16* Sl = Ws;  // [64 l][264]
  #pragma unroll
  for(int nt=0;nt<16;nt++)
    #pragma unroll
    for(int r=0;r<4;r++)
      Sl[(w*16 + quad*4 + r)*264 + nt*16 + lr] = f2bf(acc[nt][r]);
  __syncthreads();
  #pragma unroll
  for(int pass=0; pass<8; pass++){
    int idx = t + pass*256, l = idx >> 5, c16 = idx & 31;
    int e0 = c16*8;
    uint4 v = *(uint4*)&Sl[l*264 + e0];
    size_t row = (size_t)bm*4096 + l0 + l;
    if(e0 < 128) *(uint4*)&xcb[row*128 + e0] = v;
    else         *(uint4*)&zb[row*128 + e0 - 128] = v;
  }
}

// ---------------- K3: causal depthwise conv1d(4) + bias + SiLU -> xs (bf16)
// 4 consecutive l per thread: 7 input loads / 4 outputs, weights loaded once.
__global__ __launch_bounds__(256) void k_conv(const bf16* __restrict__ xcb, const void* __restrict__ cw,
                                              const void* __restrict__ cb, bf16* __restrict__ xsb,
                                              const int* __restrict__ modep){
  const int md = *modep;
  int g = blockIdx.x*256 + threadIdx.x;   // 2,097,152 = 16 bm x 1024 l4 x 128 d
  int d = g & 127;
  int t4 = g >> 7;
  int l4 = t4 & 1023;
  int bm = t4 >> 10;
  int l0 = l4 << 2;
  size_t base = ((size_t)bm*4096 + l0)*128 + d;
  const bf16* p = xcb + base;
  float w0 = ld(cw,(size_t)(d<<2)+0,md), w1 = ld(cw,(size_t)(d<<2)+1,md);
  float w2 = ld(cw,(size_t)(d<<2)+2,md), w3 = ld(cw,(size_t)(d<<2)+3,md);
  float bv = ld(cb,(size_t)d,md);
  float xm3, xm2, xm1;
  if(l4 > 0){ xm3 = bf2f(p[-384]); xm2 = bf2f(p[-256]); xm1 = bf2f(p[-128]); }
  else      { xm3 = 0.f; xm2 = 0.f; xm1 = 0.f; }
  float x0 = bf2f(p[0]), x1 = bf2f(p[128]), x2 = bf2f(p[256]), x3 = bf2f(p[384]);
  float y0 = fmaf(w0,xm3, fmaf(w1,xm2, fmaf(w2,xm1, fmaf(w3,x0, bv))));
  float y1 = fmaf(w0,xm2, fmaf(w1,xm1, fmaf(w2,x0,  fmaf(w3,x1, bv))));
  float y2 = fmaf(w0,xm1, fmaf(w1,x0,  fmaf(w2,x1,  fmaf(w3,x2, bv))));
  float y3 = fmaf(w0,x0,  fmaf(w1,x1,  fmaf(w2,x2,  fmaf(w3,x3, bv))));
  bf16* o = xsb + base;
  o[0]   = f2bf(y0 / (1.f + __expf(-y0)));
  o[128] = f2bf(y1 / (1.f + __expf(-y1)));
  o[256] = f2bf(y2 / (1.f + __expf(-y2)));
  o[384] = f2bf(y3 / (1.f + __expf(-y3)));
}

// ---- packed power chain: p_j = (e1^(2j+1), e1^(2j+2)) for j=0..7, from scalar e1.
#define PTREE2(P, e1) \
  float e2s=(e1)*(e1), e4s=e2s*e2s, e8s=e4s*e4s; \
  f2_t P##0={(e1),e2s}; \
  f2_t P##1=P##0*(f2_t){e2s,e2s}; \
  f2_t e4v_={e4s,e4s}; f2_t P##2=P##0*e4v_, P##3=P##1*e4v_; \
  f2_t e8v_={e8s,e8s}; f2_t P##4=P##0*e8v_, P##5=P##1*e8v_, P##6=P##2*e8v_, P##7=P##3*e8v_;

// ---------------- K4+K5a fused: per block = (bm, 64-row tile):
//  phase 1: stage xs rows -> As[64][136] bf16 (serves MFMA A AND scan u-tile),
//           stage x_proj weights (inline cvt, zero-pad e>=36) -> Ws[64][136],
//  phase 2: MFMA xdbl = xs @ W^T  -> global xdbl (for scan3) + LDS sh (aliased over Ws),
//  phase 3: two 32-step scan1 chunks (t>>7 = chunk), R7 inner loop, u from As.
__global__ __launch_bounds__(256) void k_cxs1(const bf16* __restrict__ xsb, const void* __restrict__ xpw,
                                              float* __restrict__ xdbl,
                                              const void* __restrict__ dtw, const void* __restrict__ dtb,
                                              const void* __restrict__ Alog,
                                              float* __restrict__ CP, bf16* __restrict__ CSb,
                                              const int* __restrict__ modep){
  __shared__ bf16 As[64*136];
  __shared__ bf16 Ws[64*136];          // aliased by sh (64*36 f32 = 9216B < 17408B) after MFMA
  float* sh = (float*)Ws;
  const int md = *modep;
  int t = threadIdx.x;
  int bm = blockIdx.x >> 6, lt = blockIdx.x & 63;
  size_t row0g = (size_t)bm*4096 + (lt << 6);
  // stage As: 64 rows x 128 d, uint4 coalesced
  #pragma unroll
  for(int pass=0; pass<4; pass++){
    int idx = t + pass*256, r = idx >> 4, ch = idx & 15;
    *(uint4*)&As[r*136 + ch*8] = *(const uint4*)&xsb[(row0g + r)*128 + ch*8];
  }
  // stage Ws with inline convert + zero-pad
  for(int idx = t; idx < 8192; idx += 256){
    int e = idx >> 7, k = idx & 127;
    Ws[e*136 + k] = (e < 36) ? f2bf(ld(xpw, (size_t)e*128 + k, md)) : f2bf(0.f);
  }
  __syncthreads();
  int lane = t & 63, w = t >> 6, quad = lane >> 4, lr = lane & 15;
  f4_t acc[3];
  #pragma unroll
  for(int nt=0;nt<3;nt++) acc[nt] = (f4_t){0.f,0.f,0.f,0.f};
  #pragma unroll
  for(int kk=0; kk<128; kk+=32){
    bf8_t a = *(const bf8_t*)&As[(w*16 + lr)*136 + kk + quad*8];
    #pragma unroll
    for(int nt=0;nt<3;nt++){
      bf8_t bb = *(const bf8_t*)&Ws[(nt*16 + lr)*136 + kk + quad*8];
      acc[nt] = MFMA16(a, bb, acc[nt]);
    }
  }
  __syncthreads();   // all Ws reads done; safe to overwrite with sh
  #pragma unroll
  for(int nt=0;nt<3;nt++){
    int e = nt*16 + lr;
    if(e < 36){
      #pragma unroll
      for(int r=0;r<4;r++){
        int row = w*16 + quad*4 + r;
        float v = acc[nt][r];
        sh[row*36 + e] = v;
        xdbl[(row0g + row)*36 + e] = v;
      }
    }
  }
  // ---- scan prologue
  int d = t & 127, chunk = t >> 7;
  float A[16];
  #pragma unroll
  for(int s=0;s<16;s++) A[s] = -expf(ld(Alog, (size_t)((d<<4)+s), md));
  float A0 = A[0];
  int fastf = 1;
  #pragma unroll
  for(int s=0;s<16;s++){
    float n = (float)(s+1);
    if(fabsf(A[s] - n*A0) > 2e-3f*fabsf(n*A0)) fastf = 0;
  }
  fastf = __all(fastf);
  float wdt[4];
  #pragma unroll
  for(int j=0;j<4;j++) wdt[j] = ld(dtw, (size_t)((d<<2)+j), md);
  float bdt = ld(dtb, (size_t)d, md);
  __syncthreads();
  f2_t h2[8];
  #pragma unroll
  for(int j=0;j<8;j++) h2[j] = (f2_t){0.f,0.f};
  float sumd = 0.f;
  const float* shc = sh + chunk*32*36;
  const bf16* uc = As + chunk*32*136;
  if(fastf){
    #pragma unroll
    for(int tt=0;tt<32;tt++){
      const float* r = shc + tt*36;
      float4 dt4 = *(const float4*)r;
      float v = fmaf(dt4.x,wdt[0], fmaf(dt4.y,wdt[1], fmaf(dt4.z,wdt[2], fmaf(dt4.w,wdt[3], bdt))));
      float dv = fmaxf(v,0.f) + __logf(1.f + __expf(-fabsf(v)));
      float u = bf2f(uc[tt*136 + d]);
      float du = dv*u; sumd += dv;
      const f2_t* B2 = (const f2_t*)(r+4);
      float e1 = __expf(dv*A0);
      PTREE2(p, e1);
      f2_t du2 = {du,du};
      h2[0] = h2[0]*p0 + du2*B2[0];
      h2[1] = h2[1]*p1 + du2*B2[1];
      h2[2] = h2[2]*p2 + du2*B2[2];
      h2[3] = h2[3]*p3 + du2*B2[3];
      h2[4] = h2[4]*p4 + du2*B2[4];
      h2[5] = h2[5]*p5 + du2*B2[5];
      h2[6] = h2[6]*p6 + du2*B2[6];
      h2[7] = h2[7]*p7 + du2*B2[7];
    }
  } else {
    for(int tt=0;tt<32;tt++){
      const float* r = shc + tt*36;
      float4 dt4 = *(const float4*)r;
      float v = fmaf(dt4.x,wdt[0], fmaf(dt4.y,wdt[1], fmaf(dt4.z,wdt[2], fmaf(dt4.w,wdt[3], bdt))));
      float dv = fmaxf(v,0.f) + __logf(1.f + __expf(-fabsf(v)));
      float u = bf2f(uc[tt*136 + d]);
      float du = dv*u; sumd += dv;
      const float* Bp = r + 4;
      #pragma unroll
      for(int j=0;j<8;j++){
        f2_t e = { __expf(dv*A[2*j]), __expf(dv*A[2*j+1]) };
        f2_t bb = { Bp[2*j], Bp[2*j+1] };
        h2[j] = h2[j]*e + (f2_t){du,du}*bb;
      }
    }
  }
  int c = lt*2 + chunk;
  size_t ob = ((size_t)(bm*128 + c)*128 + d) << 4;
  if(fastf){
    float qv = __expf(sumd*A0);
    PTREE2(P, qv);
    *(f2_t*)&CP[ob+ 0]=P0; *(f2_t*)&CP[ob+ 2]=P1; *(f2_t*)&CP[ob+ 4]=P2; *(f2_t*)&CP[ob+ 6]=P3;
    *(f2_t*)&CP[ob+ 8]=P4; *(f2_t*)&CP[ob+10]=P5; *(f2_t*)&CP[ob+12]=P6; *(f2_t*)&CP[ob+14]=P7;
  } else {
    #pragma unroll
    for(int s=0;s<16;s++) CP[ob+s] = __expf(sumd*A[s]);
  }
  __align__(16) bf16 pk[8];
  #pragma unroll
  for(int j=0;j<4;j++){ pk[2*j] = f2bf(h2[j].x); pk[2*j+1] = f2bf(h2[j].y); }
  *(uint4*)&CSb[ob] = *(uint4*)pk;
  #pragma unroll
  for(int j=0;j<4;j++){ pk[2*j] = f2bf(h2[4+j].x); pk[2*j+1] = f2bf(h2[4+j].y); }
  *(uint4*)&CSb[ob+8] = *(uint4*)pk;
}

// ---------------- K5b: scan phase2 — combine 128 chunks; CP[c] becomes h_start of chunk c.
__global__ __launch_bounds__(64) void k_scan2(float* __restrict__ CP, const bf16* __restrict__ CSb){
  int g = blockIdx.x*64 + threadIdx.x;   // 32768
  int bm = g >> 11, ds = g & 2047;
  size_t base = ((size_t)bm << 18) + ds; // bm*128*2048 + ds
  float Pb[8], Sb[8];
  #pragma unroll
  for(int j=0;j<8;j++){
    size_t idx = base + ((size_t)j << 11);
    Pb[j] = CP[idx]; Sb[j] = bf2f(CSb[idx]);
  }
  float h = 0.f;
  #pragma unroll
  for(int grp=0; grp<16; grp++){
    float Pc[8], Sc[8];
    #pragma unroll
    for(int j=0;j<8;j++){ Pc[j]=Pb[j]; Sc[j]=Sb[j]; }
    if(grp < 15){
      #pragma unroll
      for(int j=0;j<8;j++){
        size_t idx = base + ((size_t)((grp+1)*8 + j) << 11);
        Pb[j] = CP[idx]; Sb[j] = bf2f(CSb[idx]);
      }
    }
    #pragma unroll
    for(int j=0;j<8;j++){
      size_t idx = base + ((size_t)(grp*8 + j) << 11);
      CP[idx] = h;
      h = fmaf(Pc[j], h, Sc[j]);
    }
  }
}

// ---------------- K5c+K6 fused: scan phase3 + out_proj + skip.
// Scan: R7 inner loop; y written IN PLACE over the consumed u slot in su[32][136].
// out_proj MFMA B-fragments read DIRECTLY from global wout (16KB, L2-hot) — no LDS
// weight tile. LDS = 13.3KB -> all 8 blocks/CU resident.
__global__ __launch_bounds__(128) void k_scan3o(const bf16* __restrict__ zb, const bf16* __restrict__ xsb,
                                                const float* __restrict__ xdbl,
                                                const void* __restrict__ dtw, const void* __restrict__ dtb,
                                                const void* __restrict__ Alog, const void* __restrict__ Dw,
                                                const float* __restrict__ CP,
                                                const bf16* __restrict__ xnb, const bf16* __restrict__ wout,
                                                const void* __restrict__ ss, bf16* __restrict__ ymb,
                                                const int* __restrict__ modep){
  __shared__ float sh[32*36];          // xdbl tile; aliased post-loop by Sl bf16[32*72]
  __shared__ bf16 su[32*136];          // u staged; y written in place (padded for MFMA A)
  const int md = *modep;
  int t = threadIdx.x;
  int d = t;
  int bm = blockIdx.x >> 7, c = blockIdx.x & 127;
  int p = bm >> 2, b = bm & 3;
  size_t row0 = (size_t)bm*4096 + (c<<5);
  {
    const float4* src = (const float4*)(xdbl + row0*36);
    for(int idx = d; idx < 288; idx += 128) ((float4*)sh)[idx] = src[idx];
    const uint4* gu = (const uint4*)(xsb + row0*128);
    uint4* lu = (uint4*)su;
    #pragma unroll
    for(int j=0;j<4;j++){
      int i = d + j*128;                     // 512 u4: row=i>>4, col8=i&15
      lu[(i>>4)*17 + (i&15)] = gu[i];
    }
  }
  float A[16];
  #pragma unroll
  for(int s=0;s<16;s++) A[s] = -expf(ld(Alog, (size_t)((d<<4)+s), md));
  float A0 = A[0];
  int fastf = 1;
  #pragma unroll
  for(int s=0;s<16;s++){
    float n = (float)(s+1);
    if(fabsf(A[s] - n*A0) > 2e-3f*fabsf(n*A0)) fastf = 0;
  }
  fastf = __all(fastf);
  float wdt[4];
  #pragma unroll
  for(int j=0;j<4;j++) wdt[j] = ld(dtw, (size_t)((d<<2)+j), md);
  float bdt = ld(dtb, (size_t)d, md);
  float Dd = ld(Dw, (size_t)d, md);
  size_t hb = ((size_t)(bm*128 + c)*128 + d) << 4;
  f2_t h2[8];
  #pragma unroll
  for(int j=0;j<8;j++) h2[j] = *(const f2_t*)&CP[hb + 2*j];
  __syncthreads();
  if(fastf){
    #pragma unroll
    for(int tt=0;tt<32;tt++){
      const float* r = sh + tt*36;
      size_t bg = (row0 + tt)*128 + d;
      float zv = bf2f(zb[bg]);          // issued early; consumed at end of step
      float4 dt4 = *(const float4*)r;
      float v = fmaf(dt4.x,wdt[0], fmaf(dt4.y,wdt[1], fmaf(dt4.z,wdt[2], fmaf(dt4.w,wdt[3], bdt))));
      float dv = fmaxf(v,0.f) + __logf(1.f + __expf(-fabsf(v)));
      float u  = bf2f(su[tt*136 + d]);
      float du = dv*u;
      const f2_t* B2 = (const f2_t*)(r+4);
      const f2_t* C2 = (const f2_t*)(r+20);
      float e1 = __expf(dv*A0);
      PTREE2(p_, e1);
      f2_t du2 = {du,du};
      f2_t ya = {0.f,0.f}, yb = {0.f,0.f};
      h2[0] = h2[0]*p_0 + du2*B2[0];  ya += h2[0]*C2[0];
      h2[1] = h2[1]*p_1 + du2*B2[1];  yb += h2[1]*C2[1];
      h2[2] = h2[2]*p_2 + du2*B2[2];  ya += h2[2]*C2[2];
      h2[3] = h2[3]*p_3 + du2*B2[3];  yb += h2[3]*C2[3];
      h2[4] = h2[4]*p_4 + du2*B2[4];  ya += h2[4]*C2[4];
      h2[5] = h2[5]*p_5 + du2*B2[5];  yb += h2[5]*C2[5];
      h2[6] = h2[6]*p_6 + du2*B2[6];  ya += h2[6]*C2[6];
      h2[7] = h2[7]*p_7 + du2*B2[7];  yb += h2[7]*C2[7];
      float y = (ya.x + ya.y) + (yb.x + yb.y);
      float yv = (y + u*Dd) * (zv / (1.f + __expf(-zv)));
      su[tt*136 + d] = f2bf(yv);       // in-place: u slot consumed, y becomes MFMA A
    }
  } else {
    for(int tt=0;tt<32;tt++){
      const float* r = sh + tt*36;
      size_t bg = (row0 + tt)*128 + d;
      float zv = bf2f(zb[bg]);
      float4 dt4 = *(const float4*)r;
      float v = fmaf(dt4.x,wdt[0], fmaf(dt4.y,wdt[1], fmaf(dt4.z,wdt[2], fmaf(dt4.w,wdt[3], bdt))));
      float dv = fmaxf(v,0.f) + __logf(1.f + __expf(-fabsf(v)));
      float u  = bf2f(su[tt*136 + d]);
      float du = dv*u;
      const float* Bp = r + 4;
      const float* Cp = r + 20;
      f2_t ya = {0.f,0.f};
      #pragma unroll
      for(int j=0;j<8;j++){
        f2_t e = { __expf(dv*A[2*j]), __expf(dv*A[2*j+1]) };
        f2_t bb = { Bp[2*j], Bp[2*j+1] };
        f2_t cc = { Cp[2*j], Cp[2*j+1] };
        h2[j] = h2[j]*e + (f2_t){du,du}*bb;
        ya += h2[j]*cc;
      }
      float y = ya.x + ya.y;
      float yv = (y + u*Dd) * (zv / (1.f + __expf(-zv)));
      su[tt*136 + d] = f2bf(yv);
    }
  }
  __syncthreads();
  // out_proj MFMA: M=32, N=64, K=128; B-fragments from global (L2-hot 16KB weights)
  int lane = t & 63, w = t >> 6, quad = lane >> 4, lr = lane & 15;
  f4_t acc[4];
  #pragma unroll
  for(int nt=0;nt<4;nt++) acc[nt] = (f4_t){0.f,0.f,0.f,0.f};
  #pragma unroll
  for(int kk=0; kk<128; kk+=32){
    bf8_t a = *(const bf8_t*)&su[(w*16 + lr)*136 + kk + quad*8];
    #pragma unroll
    for(int nt=0;nt<4;nt++){
      bf8_t bb = *(const bf8_t*)&wout[(size_t)(nt*16 + lr)*128 + kk + quad*8];
      acc[nt] = MFMA16(a, bb, acc[nt]);
    }
  }
  bf16* Sl = (bf16*)sh;   // [32 l][72]
  #pragma unroll
  for(int nt=0;nt<4;nt++)
    #pragma unroll
    for(int r=0;r<4;r++)
      Sl[(w*16 + quad*4 + r)*72 + nt*16 + lr] = f2bf(acc[nt][r]);
  __syncthreads();
  float sv = ld(ss, 0, md);
  #pragma unroll
  for(int pass=0; pass<2; pass++){
    int idx = t + pass*128;            // 256 uint4 = 32 rows x 8 u4
    int row = idx >> 3, ch = idx & 7;
    size_t gi = ((size_t)b*4096 + (c<<5) + row)*256 + p*64 + ch*8;
    uint4 yv = *(uint4*)&Sl[row*72 + ch*8];
    uint4 xv = *(const uint4*)&xnb[gi];
    const bf16* y8 = (const bf16*)&yv;
    const bf16* x8 = (const bf16*)&xv;
    uint4 ov; bf16* o8 = (bf16*)&ov;
    #pragma unroll
    for(int j=0;j<8;j++) o8[j] = f2bf(fmaf(sv, bf2f(x8[j]), bf2f(y8[j])));
    *(uint4*)&ymb[gi] = ov;
  }
}

// ---------------- K7: LayerNorm2 in-place on ym (bf16 rows of 256)
__global__ __launch_bounds__(256) void k_ln2(bf16* __restrict__ ymb, const void* __restrict__ gam,
                                             const void* __restrict__ bet, const int* __restrict__ modep){
  const int md = *modep;
  int lane = threadIdx.x & 63, wv = threadIdx.x >> 6;
  size_t row = (size_t)blockIdx.x*4 + wv;
  bf16* rp = ymb + row*256 + (lane<<2);
  __align__(8) bf16 raw[4];
  *(ushort4*)raw = *(const ushort4*)rp;
  float v[4];
  #pragma unroll
  for(int i=0;i<4;i++) v[i] = bf2f(raw[i]);
  float s = v[0]+v[1]+v[2]+v[3];
  float s2 = v[0]*v[0]+v[1]*v[1]+v[2]*v[2]+v[3]*v[3];
  s = wred(s); s2 = wred(s2);
  float mu = s*(1.f/256.f);
  float rs = rsqrtf(s2*(1.f/256.f) - mu*mu + 1e-5f);
  int c = lane << 2;
  #pragma unroll
  for(int i=0;i<4;i++) raw[i] = f2bf((v[i]-mu)*rs*ld(gam,c+i,md) + ld(bet,c+i,md));
  *(ushort4*)rp = *(ushort4*)raw;
}

// ---------------- K8: proj MFMA (M=16384, K=256, N=256) + bias, transposed store -> outb[b,o,l]
// 32-row tiles -> 512 blocks (2 blocks/CU). Each wave: 16 rows x 128 outputs.
// + fused theta from the full-o LDS tile (t<32 covers the 32 rows).
__global__ __launch_bounds__(256) void k_proj(const bf16* __restrict__ ymb, const bf16* __restrict__ wb,
                                              const void* __restrict__ pb, bf16* __restrict__ outbb,
                                              const void* __restrict__ tw, const void* __restrict__ tb2,
                                              float* __restrict__ theta, const int* __restrict__ modep){
  __shared__ bf16 As[32*72];
  __shared__ bf16 Ws[256*72];
  const int md = *modep;
  int t = threadIdx.x;
  int row0 = blockIdx.x << 5;
  int b = row0 >> 12, l0 = row0 & 4095;
  int lane = t & 63, w = t >> 6, quad = lane >> 4, lr = lane & 15;
  int rg = w & 1, ch2 = w >> 1;
  f4_t acc[8];
  #pragma unroll
  for(int nt=0;nt<8;nt++) acc[nt] = (f4_t){0.f,0.f,0.f,0.f};
  for(int kb=0; kb<4; kb++){
    if(kb) __syncthreads();
    int k0 = kb << 6;
    { int r = t >> 3, ch = t & 7;
      *(uint4*)&As[r*72 + ch*8] = *(const uint4*)&ymb[((size_t)(row0 + r))*256 + k0 + ch*8]; }
    #pragma unroll
    for(int pass=0; pass<8; pass++){
      int idx = t + pass*256, e = idx >> 3, ch = idx & 7;
      *(uint4*)&Ws[e*72 + ch*8] = *(const uint4*)&wb[(size_t)e*256 + k0 + ch*8];
    }
    __syncthreads();
    #pragma unroll
    for(int kk=0; kk<64; kk+=32){
      bf8_t a = *(const bf8_t*)&As[(rg*16 + lr)*72 + kk + quad*8];
      #pragma unroll
      for(int nt=0;nt<8;nt++){
        bf8_t bb = *(const bf8_t*)&Ws[(ch2*128 + nt*16 + lr)*72 + kk + quad*8];
        acc[nt] = MFMA16(a, bb, acc[nt]);
      }
    }
  }
  __syncthreads();
  bf16* Sl = Ws;   // [256 o][40 l]
  #pragma unroll
  for(int nt=0;nt<8;nt++){
    int o = ch2*128 + nt*16 + lr;
    float bv = ld(pb, (size_t)o, md);
    #pragma unroll
    for(int r=0;r<4;r++)
      Sl[o*40 + rg*16 + quad*4 + r] = f2bf(acc[nt][r] + bv);
  }
  __syncthreads();
  #pragma unroll
  for(int pass=0; pass<4; pass++){
    int idx = t + pass*256, o = idx >> 2, q = idx & 3;
    uint4 v = *(uint4*)&Sl[o*40 + q*8];
    *(uint4*)&outbb[((size_t)(b*256 + o) << 12) + l0 + q*8] = v;
  }
  // fused theta (t<32: one thread per row of this 32-row tile)
  if(t < 32){
    float acc2 = 0.f;
    #pragma unroll 8
    for(int o=0;o<256;o++)
      acc2 = fmaf(bf2f(Sl[o*40 + t]), ld(tw, (size_t)o, md), acc2);
    float v = acc2 + ld(tb2, 0, md);
    theta[((size_t)b << 12) + l0 + t] = 1.f / (1.f + __expf(-v));
  }
}

// ---------------- K9b: depthwise 3x3 + CDC + exact GELU -> gbuf (bf16)
// 4 consecutive w per thread: 18 guarded loads / 4 outputs, theta as float4, packed 8B store.
__global__ __launch_bounds__(256) void k_cdc(const bf16* __restrict__ outbb, const float* __restrict__ theta,
                                             const void* __restrict__ cw, bf16* __restrict__ gbufb,
                                             const int* __restrict__ modep){
  const int md = *modep;
  int g = blockIdx.x*256 + threadIdx.x;   // 1,048,576 = 4 b x 256 c x 64 h x 16 w4
  int w4 = g & 15;
  int h0 = (g >> 4) & 63;
  int c  = (g >> 10) & 255;
  int b  = g >> 18;
  int w0 = w4 << 2;
  float wk[9]; float ks = 0.f;
  #pragma unroll
  for(int j=0;j<9;j++){ wk[j] = ld(cw, (size_t)c*9 + j, md); ks += wk[j]; }
  const bf16* base = outbb + (((size_t)b*256 + c) << 12);
  float X[3][6];
  #pragma unroll
  for(int dy=0;dy<3;dy++){
    int hh = h0 + dy - 1;
    #pragma unroll
    for(int dx=0;dx<6;dx++){
      int ww = w0 + dx - 1;
      X[dy][dx] = (hh>=0 && hh<64 && ww>=0 && ww<64) ? bf2f(base[(hh<<6)+ww]) : 0.f;
    }
  }
  float4 th = *(const float4*)&theta[((size_t)b<<12) + (h0<<6) + w0];
  float thv[4] = {th.x, th.y, th.z, th.w};
  __align__(8) bf16 outp[4];
  #pragma unroll
  for(int k=0;k<4;k++){
    float on = 0.f;
    #pragma unroll
    for(int dy=0;dy<3;dy++)
      #pragma unroll
      for(int dx=0;dx<3;dx++)
        on = fmaf(X[dy][k+dx], wk[dy*3+dx], on);
    float ctr  = X[1][k+1];
    float edge = on - ctr*ks;
    float cd   = fmaf(thv[k], edge, on);
    outp[k] = f2bf(0.5f * cd * (1.f + erff(cd * 0.70710678118654752f)));
  }
  *(ushort4*)&gbufb[(((size_t)b*256 + c) << 12) + (h0<<6) + w0] = *(ushort4*)outp;
}

// ---------------- K10: 1x1 pw MFMA + residual, dual-dtype store.
// 128-hw tiles -> 512 blocks (2 blocks/CU), LDS 27KB.
__global__ __launch_bounds__(256) void k_pw(const bf16* __restrict__ gbufb, const bf16* __restrict__ outbb,
                                            const bf16* __restrict__ wb, void* __restrict__ outp,
                                            const int* __restrict__ modep){
  __shared__ bf16 As[64*72];      // weight tile [64 o][64 c]
  __shared__ bf16 Bs[128*72];     // act tile [128 hw][64 c]
  const int md = *modep;
  int t = threadIdx.x;
  int b  = blockIdx.x >> 7;
  int ot = (blockIdx.x >> 5) & 3;
  int ht = blockIdx.x & 31;
  int o0 = ot << 6, hw0 = ht << 7;
  int lane = t & 63, w = t >> 6, quad = lane >> 4, lr = lane & 15;
  f4_t acc[8];
  #pragma unroll
  for(int nt=0;nt<8;nt++) acc[nt] = (f4_t){0.f,0.f,0.f,0.f};
  for(int kb=0; kb<4; kb++){
    if(kb) __syncthreads();
    int k0 = kb << 6;
    #pragma unroll
    for(int pass=0; pass<2; pass++){
      int idx = t + pass*256, r = idx >> 3, ch = idx & 7;
      *(uint4*)&As[r*72 + ch*8] = *(const uint4*)&wb[(size_t)(o0 + r)*256 + k0 + ch*8];
    }
    #pragma unroll
    for(int pass=0; pass<4; pass++){
      int idx = t + pass*256, cc = idx >> 4, hc = idx & 15;
      uint4 gv = *(const uint4*)&gbufb[((size_t)(b*256 + k0 + cc) << 12) + hw0 + hc*8];
      const bf16* g8 = (const bf16*)&gv;
      #pragma unroll
      for(int j=0;j<8;j++) Bs[(hc*8 + j)*72 + cc] = g8[j];
    }
    __syncthreads();
    #pragma unroll
    for(int kk=0; kk<64; kk+=32){
      bf8_t a = *(const bf8_t*)&As[(w*16 + lr)*72 + kk + quad*8];
      #pragma unroll
      for(int nt=0;nt<8;nt++){
        bf8_t bb = *(const bf8_t*)&Bs[(nt*16 + lr)*72 + kk + quad*8];
        acc[nt] = MFMA16(a, bb, acc[nt]);
      }
    }
  }
  __syncthreads();
  bf16* Sl = Bs;  // [64 o][136 hw]
  #pragma unroll
  for(int nt=0;nt<8;nt++)
    #pragma unroll
    for(int r=0;r<4;r++)
      Sl[(w*16 + quad*4 + r)*136 + nt*16 + lr] = f2bf(acc[nt][r]);
  __syncthreads();
  #pragma unroll
  for(int pass=0; pass<4; pass++){
    int idx = t + pass*256, ol = idx >> 4, c16 = idx & 15;
    size_t ro = ((size_t)(b*256 + o0 + ol) << 12) + hw0 + c16*8;
    uint4 sv = *(uint4*)&Sl[ol*136 + c16*8];
    uint4 rv = *(const uint4*)&outbb[ro];
    const bf16* s8 = (const bf16*)&sv;
    const bf16* r8 = (const bf16*)&rv;
    if(md){
      float4 f0, f1;
      f0.x = bf2f(s8[0]) + bf2f(r8[0]); f0.y = bf2f(s8[1]) + bf2f(r8[1]);
      f0.z = bf2f(s8[2]) + bf2f(r8[2]); f0.w = bf2f(s8[3]) + bf2f(r8[3]);
      f1.x = bf2f(s8[4]) + bf2f(r8[4]); f1.y = bf2f(s8[5]) + bf2f(r8[5]);
      f1.z = bf2f(s8[6]) + bf2f(r8[6]); f1.w = bf2f(s8[7]) + bf2f(r8[7]);
      *(float4*)&((float*)outp)[ro]     = f0;
      *(float4*)&((float*)outp)[ro + 4] = f1;
    } else {
      uint4 ov; bf16* o8 = (bf16*)&ov;
      #pragma unroll
      for(int j=0;j<8;j++) o8[j] = f2bf(bf2f(s8[j]) + bf2f(r8[j]));
      *(uint4*)&((bf16*)outp)[ro] = ov;
    }
  }
}

extern "C" void kernel_launch(void* const* d_in, const int* in_sizes, int n_in,
                              void* d_out, int out_size, void* d_ws, size_t ws_size,
                              hipStream_t stream){
  const void* x      = d_in[0];
  const void* ln_g   = d_in[1];
  const void* ln_b   = d_in[2];
  const void* inw    = d_in[3];
  const void* convw  = d_in[4];
  const void* convb  = d_in[5];
  const void* xpw    = d_in[6];
  const void* dtw    = d_in[7];
  const void* dtb    = d_in[8];
  const void* Alog   = d_in[9];
  const void* Dw     = d_in[10];
  const void* outw   = d_in[11];
  const void* sscale = d_in[12];
  const void* projw  = d_in[13];
  const void* projb  = d_in[14];
  const void* cdcw   = d_in[15];
  const void* thw    = d_in[16];
  const void* thb    = d_in[17];
  const void* pww    = d_in[18];
  float* ws = (float*)d_ws;

  // ---- Workspace layout, f32 SLOT offsets ----
  // [0, 2097152)         xnb  bf16 [4][4096][256]        live ln1..scan3o (skip input)
  // [2097152, 6291456)   xcb  bf16 [16][4096][128]       live inproj..conv
  //    alias             CP   f32  [16][128][128][16]    live cxs1..scan3o (4,194,304 slots exact)
  //    alias [4194304,6291456)  outbb bf16 [4][256][4096] live proj..pw
  // [6291456, 10485760)  zb   bf16 [16][4096][128]       live inproj..scan3o (read-only there)
  //    alias [6291456,8388608)  gbufb bf16 [4][256][4096] live cdc..pw
  // [10485760, 14680064) xsb  bf16 [16][4096][128]       live conv..scan3o
  //    alias             theta f32 [4][4096]             live proj..cdc (written by k_proj)
  // [14680064, 17039360) xdbl f32 [16][4096][36]         live cxs1..scan3o
  // [17039360]           flag int
  // [17039364, 17117188) bf16 weight copies (155648 elems)
  // d_out scratch: CSb bf16[4,194,304] (cxs1..scan2); then ymb bf16 [4][4096][256]
  // (scan3o..proj); k_pw fully overwrites d_out with the final output.
  bf16*  xnb   = (bf16*)(ws);
  bf16*  xcb   = (bf16*)(ws + 2097152);
  float* CP    = ws + 2097152;
  bf16*  outbb = (bf16*)(ws + 4194304);
  bf16*  zb    = (bf16*)(ws + 6291456);
  bf16*  gbufb = (bf16*)(ws + 6291456);
  bf16*  xsb   = (bf16*)(ws + 10485760);
  float* theta = ws + 10485760;
  float* xdbl  = ws + 14680064;
  int*   flag  = (int*)(ws + 17039360);
  bf16*  wsb   = (bf16*)(ws + 17039364);
  bf16*  inwb  = wsb;
  bf16*  outwb = wsb + 16384;
  bf16*  projwb= wsb + 24576;
  bf16*  pwwb  = wsb + 90112;
  bf16*  CSb   = (bf16*)d_out;
  bf16*  ymb   = (bf16*)d_out;

  k_detect <<<1,    256, 0, stream>>>((const unsigned short*)x, flag);
  k_wcvt   <<<608,  256, 0, stream>>>(inw, outw, projw, pww, wsb, flag);
  k_ln1    <<<256,  256, 0, stream>>>(x, ln_g, ln_b, xnb, flag);
  k_inproj <<<1024, 256, 0, stream>>>(xnb, inwb, xcb, zb);
  k_conv   <<<8192, 256, 0, stream>>>(xcb, convw, convb, xsb, flag);
  k_cxs1   <<<1024, 256, 0, stream>>>(xsb, xpw, xdbl, dtw, dtb, Alog, CP, CSb, flag);
  k_scan2  <<<512,  64,  0, stream>>>(CP, CSb);
  k_scan3o <<<2048, 128, 0, stream>>>(zb, xsb, xdbl, dtw, dtb, Alog, Dw, CP,
                                      xnb, outwb, sscale, ymb, flag);
  k_ln2    <<<4096, 256, 0, stream>>>(ymb, ln_g, ln_b, flag);
  k_proj   <<<512,  256, 0, stream>>>(ymb, projwb, projb, outbb, thw, thb, theta, flag);
  k_cdc    <<<4096, 256, 0, stream>>>(outbb, theta, cdcw, gbufb, flag);
  k_pw     <<<512,  256, 0, stream>>>(gbufb, outbb, pwwb, d_out, flag);
}

// Round 14
// 303.656 us; speedup vs baseline: 1.0225x; 1.0225x over previous
//
#include <hip/hip_runtime.h>
#include <hip/hip_bf16.h>
#include <math.h>

typedef __hip_bfloat16 bf16;
typedef short bf8_t __attribute__((ext_vector_type(8)));
typedef float f4_t  __attribute__((ext_vector_type(4)));
typedef float f2_t  __attribute__((ext_vector_type(2)));
#define MFMA16(a,b,c) __builtin_amdgcn_mfma_f32_16x16x32_bf16(a,b,c,0,0,0)
#define DEV __device__ __forceinline__

DEV float bf2f(bf16 h){ return __bfloat162float(h); }
DEV bf16 f2bf(float f){ return __float2bfloat16(f); }
DEV float ld(const void* p, size_t i, int md){
  return md ? ((const float*)p)[i] : bf2f(((const bf16*)p)[i]);
}
DEV float wred(float v){
  #pragma unroll
  for(int off=32; off>0; off>>=1) v += __shfl_down(v, off, 64);
  return __shfl(v, 0, 64);
}

// ---------------- K0: detect input dtype (f32 mantissa halves decode huge as bf16)
__global__ __launch_bounds__(256) void k_detect(const unsigned short* __restrict__ xr, int* __restrict__ flag){
  __shared__ float sm[4];
  int t = threadIdx.x;
  float m = 0.f;
  for(int i=t;i<8192;i+=256){
    unsigned int w = ((unsigned int)xr[i]) << 16;
    float v = fabsf(__uint_as_float(w));
    if(v != v) v = 1e30f;
    m = fmaxf(m, v);
  }
  #pragma unroll
  for(int off=32; off>0; off>>=1) m = fmaxf(m, __shfl_down(m, off, 64));
  if((t & 63) == 0) sm[t >> 6] = m;
  __syncthreads();
  if(t == 0){
    float mm = fmaxf(fmaxf(sm[0], sm[1]), fmaxf(sm[2], sm[3]));
    *flag = (mm > 1e10f) ? 1 : 0;
  }
}

// ---------------- K0b: convert GEMM weights to bf16 workspace copies
// layout: [0,16384) inw | [16384,24576) outw | [24576,90112) projw | [90112,155648) pww
__global__ __launch_bounds__(256) void k_wcvt(const void* __restrict__ inw, const void* __restrict__ outw,
                                              const void* __restrict__ projw, const void* __restrict__ pww,
                                              bf16* __restrict__ dst, const int* __restrict__ modep){
  const int md = *modep;
  int g = blockIdx.x*256 + threadIdx.x;
  if(g >= 155648) return;
  const void* src; int i;
  if(g < 16384){ src = inw;   i = g; }
  else if(g < 24576){ src = outw;  i = g - 16384; }
  else if(g < 90112){ src = projw; i = g - 24576; }
  else { src = pww; i = g - 90112; }
  dst[g] = f2bf(ld(src, (size_t)i, md));
}

// ---------------- K1: LayerNorm over C=256 of x[B,C,L] -> xnorm[B,L,256] (bf16)
__global__ __launch_bounds__(256) void k_ln1(const void* __restrict__ x, const void* __restrict__ gam,
                                             const void* __restrict__ bet, bf16* __restrict__ xnb,
                                             const int* __restrict__ modep){
  __shared__ float sh[64*257];
  __shared__ float mus[64], rss[64];
  const int md = *modep;
  int t = threadIdx.x;
  int b = blockIdx.x >> 6, lt = blockIdx.x & 63;
  int l0 = lt << 6;
  int lane = t & 63, cg = t >> 6;
  size_t xbase = ((size_t)b << 20) + l0 + lane;
  if(md){
    const float* xp = (const float*)x + xbase;
    #pragma unroll 8
    for(int c = cg; c < 256; c += 4)
      sh[lane*257 + c] = xp[(size_t)c << 12];
  } else {
    const bf16* xp = (const bf16*)x + xbase;
    #pragma unroll 8
    for(int c = cg; c < 256; c += 4)
      sh[lane*257 + c] = bf2f(xp[(size_t)c << 12]);
  }
  __syncthreads();
  {
    int row = t >> 2, q = t & 3;
    const float* rp = sh + row*257 + q*64;
    float s = 0.f, s2 = 0.f;
    #pragma unroll 8
    for(int i=0;i<64;i++){ float v = rp[i]; s += v; s2 += v*v; }
    s  += __shfl_xor(s, 1, 64);  s2 += __shfl_xor(s2, 1, 64);
    s  += __shfl_xor(s, 2, 64);  s2 += __shfl_xor(s2, 2, 64);
    if(q == 0){
      float mu = s*(1.f/256.f);
      mus[row] = mu;
      rss[row] = rsqrtf(s2*(1.f/256.f) - mu*mu + 1e-5f);
    }
  }
  __syncthreads();
  int r0 = (t >> 6) << 4;
  #pragma unroll
  for(int k=0;k<4;k++){
    int c = (t & 63) + (k << 6);
    float gv = ld(gam, c, md), bv = ld(bet, c, md);
    #pragma unroll 4
    for(int rr=0; rr<16; rr++){
      int row = r0 + rr;
      xnb[((size_t)(b*4096 + l0 + row))*256 + c] =
        f2bf((sh[row*257 + c] - mus[row])*rss[row]*gv + bv);
    }
  }
}

// ---------------- K2: in_proj MFMA  (M=65536 rows, K=64, N=256 -> xc|z)
__global__ __launch_bounds__(256) void k_inproj(const bf16* __restrict__ xnb, const bf16* __restrict__ wb,
                                                bf16* __restrict__ xcb, bf16* __restrict__ zb){
  __shared__ bf16 As[64*72];
  __shared__ bf16 Ws[256*72];
  int t = threadIdx.x;
  int bm = blockIdx.x >> 6, lt = blockIdx.x & 63;
  int p = bm >> 2, b = bm & 3, l0 = lt << 6;
  #pragma unroll
  for(int pass=0; pass<2; pass++){
    int idx = t + pass*256, r = idx >> 3, ch = idx & 7;
    *(uint4*)&As[r*72 + ch*8] = *(const uint4*)&xnb[((size_t)(b*4096 + l0 + r))*256 + p*64 + ch*8];
  }
  #pragma unroll
  for(int pass=0; pass<8; pass++){
    int idx = t + pass*256, e = idx >> 3, ch = idx & 7;
    *(uint4*)&Ws[e*72 + ch*8] = *(const uint4*)&wb[(size_t)e*64 + ch*8];
  }
  __syncthreads();
  int lane = t & 63, w = t >> 6, quad = lane >> 4, lr = lane & 15;
  f4_t acc[16];
  #pragma unroll
  for(int nt=0;nt<16;nt++) acc[nt] = (f4_t){0.f,0.f,0.f,0.f};
  #pragma unroll
  for(int kk=0; kk<64; kk+=32){
    bf8_t a = *(const bf8_t*)&As[(w*16 + lr)*72 + kk + quad*8];
    #pragma unroll
    for(int nt=0;nt<16;nt++){
      bf8_t bb = *(const bf8_t*)&Ws[(nt*16 + lr)*72 + kk + quad*8];
      acc[nt] = MFMA16(a, bb, acc[nt]);
    }
  }
  __syncthreads();
  bf16* Sl = Ws;  // [64 l][264]
  #pragma unroll
  for(int nt=0;nt<16;nt++)
    #pragma unroll
    for(int r=0;r<4;r++)
      Sl[(w*16 + quad*4 + r)*264 + nt*16 + lr] = f2bf(acc[nt][r]);
  __syncthreads();
  #pragma unroll
  for(int pass=0; pass<8; pass++){
    int idx = t + pass*256, l = idx >> 5, c16 = idx & 31;
    int e0 = c16*8;
    uint4 v = *(uint4*)&Sl[l*264 + e0];
    size_t row = (size_t)bm*4096 + l0 + l;
    if(e0 < 128) *(uint4*)&xcb[row*128 + e0] = v;
    else         *(uint4*)&zb[row*128 + e0 - 128] = v;
  }
}

// ---------------- K3: causal depthwise conv1d(4) + bias + SiLU -> xs (bf16)
__global__ __launch_bounds__(256) void k_conv(const bf16* __restrict__ xcb, const void* __restrict__ cw,
                                              const void* __restrict__ cb, bf16* __restrict__ xsb,
                                              const int* __restrict__ modep){
  const int md = *modep;
  int g = blockIdx.x*256 + threadIdx.x;   // 2,097,152 = 16 bm x 1024 l4 x 128 d
  int d = g & 127;
  int t4 = g >> 7;
  int l4 = t4 & 1023;
  int bm = t4 >> 10;
  int l0 = l4 << 2;
  size_t base = ((size_t)bm*4096 + l0)*128 + d;
  const bf16* p = xcb + base;
  float w0 = ld(cw,(size_t)(d<<2)+0,md), w1 = ld(cw,(size_t)(d<<2)+1,md);
  float w2 = ld(cw,(size_t)(d<<2)+2,md), w3 = ld(cw,(size_t)(d<<2)+3,md);
  float bv = ld(cb,(size_t)d,md);
  float xm3, xm2, xm1;
  if(l4 > 0){ xm3 = bf2f(p[-384]); xm2 = bf2f(p[-256]); xm1 = bf2f(p[-128]); }
  else      { xm3 = 0.f; xm2 = 0.f; xm1 = 0.f; }
  float x0 = bf2f(p[0]), x1 = bf2f(p[128]), x2 = bf2f(p[256]), x3 = bf2f(p[384]);
  float y0 = fmaf(w0,xm3, fmaf(w1,xm2, fmaf(w2,xm1, fmaf(w3,x0, bv))));
  float y1 = fmaf(w0,xm2, fmaf(w1,xm1, fmaf(w2,x0,  fmaf(w3,x1, bv))));
  float y2 = fmaf(w0,xm1, fmaf(w1,x0,  fmaf(w2,x1,  fmaf(w3,x2, bv))));
  float y3 = fmaf(w0,x0,  fmaf(w1,x1,  fmaf(w2,x2,  fmaf(w3,x3, bv))));
  bf16* o = xsb + base;
  o[0]   = f2bf(y0 / (1.f + __expf(-y0)));
  o[128] = f2bf(y1 / (1.f + __expf(-y1)));
  o[256] = f2bf(y2 / (1.f + __expf(-y2)));
  o[384] = f2bf(y3 / (1.f + __expf(-y3)));
}

// ---- packed power chain: p_j = (e1^(2j+1), e1^(2j+2)) for j=0..7, from scalar e1.
#define PTREE2(P, e1) \
  float e2s=(e1)*(e1), e4s=e2s*e2s, e8s=e4s*e4s; \
  f2_t P##0={(e1),e2s}; \
  f2_t P##1=P##0*(f2_t){e2s,e2s}; \
  f2_t e4v_={e4s,e4s}; f2_t P##2=P##0*e4v_, P##3=P##1*e4v_; \
  f2_t e8v_={e8s,e8s}; f2_t P##4=P##0*e8v_, P##5=P##1*e8v_, P##6=P##2*e8v_, P##7=P##3*e8v_;

// ---------------- K4+K5a fused: xproj MFMA + scan1 (see R10 notes)
__global__ __launch_bounds__(256) void k_cxs1(const bf16* __restrict__ xsb, const void* __restrict__ xpw,
                                              float* __restrict__ xdbl,
                                              const void* __restrict__ dtw, const void* __restrict__ dtb,
                                              const void* __restrict__ Alog,
                                              float* __restrict__ CP, bf16* __restrict__ CSb,
                                              const int* __restrict__ modep){
  __shared__ bf16 As[64*136];
  __shared__ bf16 Ws[64*136];          // aliased by sh (64*36 f32 = 9216B < 17408B) after MFMA
  float* sh = (float*)Ws;
  const int md = *modep;
  int t = threadIdx.x;
  int bm = blockIdx.x >> 6, lt = blockIdx.x & 63;
  size_t row0g = (size_t)bm*4096 + (lt << 6);
  #pragma unroll
  for(int pass=0; pass<4; pass++){
    int idx = t + pass*256, r = idx >> 4, ch = idx & 15;
    *(uint4*)&As[r*136 + ch*8] = *(const uint4*)&xsb[(row0g + r)*128 + ch*8];
  }
  for(int idx = t; idx < 8192; idx += 256){
    int e = idx >> 7, k = idx & 127;
    Ws[e*136 + k] = (e < 36) ? f2bf(ld(xpw, (size_t)e*128 + k, md)) : f2bf(0.f);
  }
  __syncthreads();
  int lane = t & 63, w = t >> 6, quad = lane >> 4, lr = lane & 15;
  f4_t acc[3];
  #pragma unroll
  for(int nt=0;nt<3;nt++) acc[nt] = (f4_t){0.f,0.f,0.f,0.f};
  #pragma unroll
  for(int kk=0; kk<128; kk+=32){
    bf8_t a = *(const bf8_t*)&As[(w*16 + lr)*136 + kk + quad*8];
    #pragma unroll
    for(int nt=0;nt<3;nt++){
      bf8_t bb = *(const bf8_t*)&Ws[(nt*16 + lr)*136 + kk + quad*8];
      acc[nt] = MFMA16(a, bb, acc[nt]);
    }
  }
  __syncthreads();   // all Ws reads done; safe to overwrite with sh
  #pragma unroll
  for(int nt=0;nt<3;nt++){
    int e = nt*16 + lr;
    if(e < 36){
      #pragma unroll
      for(int r=0;r<4;r++){
        int row = w*16 + quad*4 + r;
        float v = acc[nt][r];
        sh[row*36 + e] = v;
        xdbl[(row0g + row)*36 + e] = v;
      }
    }
  }
  int d = t & 127, chunk = t >> 7;
  float A[16];
  #pragma unroll
  for(int s=0;s<16;s++) A[s] = -expf(ld(Alog, (size_t)((d<<4)+s), md));
  float A0 = A[0];
  int fastf = 1;
  #pragma unroll
  for(int s=0;s<16;s++){
    float n = (float)(s+1);
    if(fabsf(A[s] - n*A0) > 2e-3f*fabsf(n*A0)) fastf = 0;
  }
  fastf = __all(fastf);
  float wdt[4];
  #pragma unroll
  for(int j=0;j<4;j++) wdt[j] = ld(dtw, (size_t)((d<<2)+j), md);
  float bdt = ld(dtb, (size_t)d, md);
  __syncthreads();
  f2_t h2[8];
  #pragma unroll
  for(int j=0;j<8;j++) h2[j] = (f2_t){0.f,0.f};
  float sumd = 0.f;
  const float* shc = sh + chunk*32*36;
  const bf16* uc = As + chunk*32*136;
  if(fastf){
    #pragma unroll
    for(int tt=0;tt<32;tt++){
      const float* r = shc + tt*36;
      float4 dt4 = *(const float4*)r;
      float v = fmaf(dt4.x,wdt[0], fmaf(dt4.y,wdt[1], fmaf(dt4.z,wdt[2], fmaf(dt4.w,wdt[3], bdt))));
      float dv = fmaxf(v,0.f) + __logf(1.f + __expf(-fabsf(v)));
      float u = bf2f(uc[tt*136 + d]);
      float du = dv*u; sumd += dv;
      const f2_t* B2 = (const f2_t*)(r+4);
      float e1 = __expf(dv*A0);
      PTREE2(p, e1);
      f2_t du2 = {du,du};
      h2[0] = h2[0]*p0 + du2*B2[0];
      h2[1] = h2[1]*p1 + du2*B2[1];
      h2[2] = h2[2]*p2 + du2*B2[2];
      h2[3] = h2[3]*p3 + du2*B2[3];
      h2[4] = h2[4]*p4 + du2*B2[4];
      h2[5] = h2[5]*p5 + du2*B2[5];
      h2[6] = h2[6]*p6 + du2*B2[6];
      h2[7] = h2[7]*p7 + du2*B2[7];
    }
  } else {
    for(int tt=0;tt<32;tt++){
      const float* r = shc + tt*36;
      float4 dt4 = *(const float4*)r;
      float v = fmaf(dt4.x,wdt[0], fmaf(dt4.y,wdt[1], fmaf(dt4.z,wdt[2], fmaf(dt4.w,wdt[3], bdt))));
      float dv = fmaxf(v,0.f) + __logf(1.f + __expf(-fabsf(v)));
      float u = bf2f(uc[tt*136 + d]);
      float du = dv*u; sumd += dv;
      const float* Bp = r + 4;
      #pragma unroll
      for(int j=0;j<8;j++){
        f2_t e = { __expf(dv*A[2*j]), __expf(dv*A[2*j+1]) };
        f2_t bb = { Bp[2*j], Bp[2*j+1] };
        h2[j] = h2[j]*e + (f2_t){du,du}*bb;
      }
    }
  }
  int c = lt*2 + chunk;
  size_t ob = ((size_t)(bm*128 + c)*128 + d) << 4;
  if(fastf){
    float qv = __expf(sumd*A0);
    PTREE2(P, qv);
    *(f2_t*)&CP[ob+ 0]=P0; *(f2_t*)&CP[ob+ 2]=P1; *(f2_t*)&CP[ob+ 4]=P2; *(f2_t*)&CP[ob+ 6]=P3;
    *(f2_t*)&CP[ob+ 8]=P4; *(f2_t*)&CP[ob+10]=P5; *(f2_t*)&CP[ob+12]=P6; *(f2_t*)&CP[ob+14]=P7;
  } else {
    #pragma unroll
    for(int s=0;s<16;s++) CP[ob+s] = __expf(sumd*A[s]);
  }
  __align__(16) bf16 pk[8];
  #pragma unroll
  for(int j=0;j<4;j++){ pk[2*j] = f2bf(h2[j].x); pk[2*j+1] = f2bf(h2[j].y); }
  *(uint4*)&CSb[ob] = *(uint4*)pk;
  #pragma unroll
  for(int j=0;j<4;j++){ pk[2*j] = f2bf(h2[4+j].x); pk[2*j+1] = f2bf(h2[4+j].y); }
  *(uint4*)&CSb[ob+8] = *(uint4*)pk;
}

// ---------------- K5b: scan phase2 — combine 128 chunks; CP[c] becomes h_start of chunk c.
__global__ __launch_bounds__(64) void k_scan2(float* __restrict__ CP, const bf16* __restrict__ CSb){
  int g = blockIdx.x*64 + threadIdx.x;   // 32768
  int bm = g >> 11, ds = g & 2047;
  size_t base = ((size_t)bm << 18) + ds; // bm*128*2048 + ds
  float Pb[8], Sb[8];
  #pragma unroll
  for(int j=0;j<8;j++){
    size_t idx = base + ((size_t)j << 11);
    Pb[j] = CP[idx]; Sb[j] = bf2f(CSb[idx]);
  }
  float h = 0.f;
  #pragma unroll
  for(int grp=0; grp<16; grp++){
    float Pc[8], Sc[8];
    #pragma unroll
    for(int j=0;j<8;j++){ Pc[j]=Pb[j]; Sc[j]=Sb[j]; }
    if(grp < 15){
      #pragma unroll
      for(int j=0;j<8;j++){
        size_t idx = base + ((size_t)((grp+1)*8 + j) << 11);
        Pb[j] = CP[idx]; Sb[j] = bf2f(CSb[idx]);
      }
    }
    #pragma unroll
    for(int j=0;j<8;j++){
      size_t idx = base + ((size_t)(grp*8 + j) << 11);
      CP[idx] = h;
      h = fmaf(Pc[j], h, Sc[j]);
    }
  }
}

// ---------------- K5c+K6 fused: scan phase3 + out_proj + skip. (R12 form: Ws in LDS.)
__global__ __launch_bounds__(128) void k_scan3o(const bf16* __restrict__ zb, const bf16* __restrict__ xsb,
                                                const float* __restrict__ xdbl,
                                                const void* __restrict__ dtw, const void* __restrict__ dtb,
                                                const void* __restrict__ Alog, const void* __restrict__ Dw,
                                                const float* __restrict__ CP,
                                                const bf16* __restrict__ xnb, const bf16* __restrict__ wout,
                                                const void* __restrict__ ss, bf16* __restrict__ ymb,
                                                const int* __restrict__ modep){
  __shared__ float sh[32*36];          // xdbl tile; aliased post-loop by Sl bf16[32*72]
  __shared__ bf16 su[32*136];          // u staged; y written in place (padded for MFMA A)
  __shared__ bf16 Ws[64*136];          // out_proj weights [64 o][128 k]
  const int md = *modep;
  int t = threadIdx.x;
  int d = t;
  int bm = blockIdx.x >> 7, c = blockIdx.x & 127;
  int p = bm >> 2, b = bm & 3;
  size_t row0 = (size_t)bm*4096 + (c<<5);
  {
    const float4* src = (const float4*)(xdbl + row0*36);
    for(int idx = d; idx < 288; idx += 128) ((float4*)sh)[idx] = src[idx];
    const uint4* gu = (const uint4*)(xsb + row0*128);
    uint4* lu = (uint4*)su;
    #pragma unroll
    for(int j=0;j<4;j++){
      int i = d + j*128;                     // 512 u4: row=i>>4, col8=i&15
      lu[(i>>4)*17 + (i&15)] = gu[i];
    }
    const uint4* gw = (const uint4*)wout;
    uint4* lw = (uint4*)Ws;
    #pragma unroll
    for(int j=0;j<8;j++){
      int i = d + j*128;                     // 1024 u4 over 64 rows x 16 u4
      lw[(i>>4)*17 + (i&15)] = gw[i];
    }
  }
  float A[16];
  #pragma unroll
  for(int s=0;s<16;s++) A[s] = -expf(ld(Alog, (size_t)((d<<4)+s), md));
  float A0 = A[0];
  int fastf = 1;
  #pragma unroll
  for(int s=0;s<16;s++){
    float n = (float)(s+1);
    if(fabsf(A[s] - n*A0) > 2e-3f*fabsf(n*A0)) fastf = 0;
  }
  fastf = __all(fastf);
  float wdt[4];
  #pragma unroll
  for(int j=0;j<4;j++) wdt[j] = ld(dtw, (size_t)((d<<2)+j), md);
  float bdt = ld(dtb, (size_t)d, md);
  float Dd = ld(Dw, (size_t)d, md);
  size_t hb = ((size_t)(bm*128 + c)*128 + d) << 4;
  f2_t h2[8];
  #pragma unroll
  for(int j=0;j<8;j++) h2[j] = *(const f2_t*)&CP[hb + 2*j];
  __syncthreads();
  if(fastf){
    #pragma unroll
    for(int tt=0;tt<32;tt++){
      const float* r = sh + tt*36;
      size_t bg = (row0 + tt)*128 + d;
      float zv = bf2f(zb[bg]);          // issued early; consumed at end of step
      float4 dt4 = *(const float4*)r;
      float v = fmaf(dt4.x,wdt[0], fmaf(dt4.y,wdt[1], fmaf(dt4.z,wdt[2], fmaf(dt4.w,wdt[3], bdt))));
      float dv = fmaxf(v,0.f) + __logf(1.f + __expf(-fabsf(v)));
      float u  = bf2f(su[tt*136 + d]);
      float du = dv*u;
      const f2_t* B2 = (const f2_t*)(r+4);
      const f2_t* C2 = (const f2_t*)(r+20);
      float e1 = __expf(dv*A0);
      PTREE2(p_, e1);
      f2_t du2 = {du,du};
      f2_t ya = {0.f,0.f}, yb = {0.f,0.f};
      h2[0] = h2[0]*p_0 + du2*B2[0];  ya += h2[0]*C2[0];
      h2[1] = h2[1]*p_1 + du2*B2[1];  yb += h2[1]*C2[1];
      h2[2] = h2[2]*p_2 + du2*B2[2];  ya += h2[2]*C2[2];
      h2[3] = h2[3]*p_3 + du2*B2[3];  yb += h2[3]*C2[3];
      h2[4] = h2[4]*p_4 + du2*B2[4];  ya += h2[4]*C2[4];
      h2[5] = h2[5]*p_5 + du2*B2[5];  yb += h2[5]*C2[5];
      h2[6] = h2[6]*p_6 + du2*B2[6];  ya += h2[6]*C2[6];
      h2[7] = h2[7]*p_7 + du2*B2[7];  yb += h2[7]*C2[7];
      float y = (ya.x + ya.y) + (yb.x + yb.y);
      float yv = (y + u*Dd) * (zv / (1.f + __expf(-zv)));
      su[tt*136 + d] = f2bf(yv);       // in-place: u slot consumed, y becomes MFMA A
    }
  } else {
    for(int tt=0;tt<32;tt++){
      const float* r = sh + tt*36;
      size_t bg = (row0 + tt)*128 + d;
      float zv = bf2f(zb[bg]);
      float4 dt4 = *(const float4*)r;
      float v = fmaf(dt4.x,wdt[0], fmaf(dt4.y,wdt[1], fmaf(dt4.z,wdt[2], fmaf(dt4.w,wdt[3], bdt))));
      float dv = fmaxf(v,0.f) + __logf(1.f + __expf(-fabsf(v)));
      float u  = bf2f(su[tt*136 + d]);
      float du = dv*u;
      const float* Bp = r + 4;
      const float* Cp = r + 20;
      f2_t ya = {0.f,0.f};
      #pragma unroll
      for(int j=0;j<8;j++){
        f2_t e = { __expf(dv*A[2*j]), __expf(dv*A[2*j+1]) };
        f2_t bb = { Bp[2*j], Bp[2*j+1] };
        f2_t cc = { Cp[2*j], Cp[2*j+1] };
        h2[j] = h2[j]*e + (f2_t){du,du}*bb;
        ya += h2[j]*cc;
      }
      float y = ya.x + ya.y;
      float yv = (y + u*Dd) * (zv / (1.f + __expf(-zv)));
      su[tt*136 + d] = f2bf(yv);
    }
  }
  __syncthreads();
  // out_proj MFMA: M=32 (rows of this chunk), N=64, K=128
  int lane = t & 63, w = t >> 6, quad = lane >> 4, lr = lane & 15;
  f4_t acc[4];
  #pragma unroll
  for(int nt=0;nt<4;nt++) acc[nt] = (f4_t){0.f,0.f,0.f,0.f};
  #pragma unroll
  for(int kk=0; kk<128; kk+=32){
    bf8_t a = *(const bf8_t*)&su[(w*16 + lr)*136 + kk + quad*8];
    #pragma unroll
    for(int nt=0;nt<4;nt++){
      bf8_t bb = *(const bf8_t*)&Ws[(nt*16 + lr)*136 + kk + quad*8];
      acc[nt] = MFMA16(a, bb, acc[nt]);
    }
  }
  bf16* Sl = (bf16*)sh;   // [32 l][72]
  #pragma unroll
  for(int nt=0;nt<4;nt++)
    #pragma unroll
    for(int r=0;r<4;r++)
      Sl[(w*16 + quad*4 + r)*72 + nt*16 + lr] = f2bf(acc[nt][r]);
  __syncthreads();
  float sv = ld(ss, 0, md);
  #pragma unroll
  for(int pass=0; pass<2; pass++){
    int idx = t + pass*128;            // 256 uint4 = 32 rows x 8 u4
    int row = idx >> 3, ch = idx & 7;
    size_t gi = ((size_t)b*4096 + (c<<5) + row)*256 + p*64 + ch*8;
    uint4 yv = *(uint4*)&Sl[row*72 + ch*8];
    uint4 xv = *(const uint4*)&xnb[gi];
    const bf16* y8 = (const bf16*)&yv;
    const bf16* x8 = (const bf16*)&xv;
    uint4 ov; bf16* o8 = (bf16*)&ov;
    #pragma unroll
    for(int j=0;j<8;j++) o8[j] = f2bf(fmaf(sv, bf2f(x8[j]), bf2f(y8[j])));
    *(uint4*)&ymb[gi] = ov;
  }
}

// ---------------- K8: proj MFMA + FUSED LayerNorm2 prologue.
// 32-row tiles -> 512 blocks. Stage full 32x256 ymb tile once, LN in LDS (8 thr/row),
// then 4 K-chunks read A from the resident normalized tile. Replaces k_ln2 entirely.
// + bias, transposed store -> outb[b,o,l]; + fused theta (t<32).
__global__ __launch_bounds__(256) void k_proj(const bf16* __restrict__ ymb, const bf16* __restrict__ wb,
                                              const void* __restrict__ pb, bf16* __restrict__ outbb,
                                              const void* __restrict__ gam, const void* __restrict__ bet,
                                              const void* __restrict__ tw, const void* __restrict__ tb2,
                                              float* __restrict__ theta, const int* __restrict__ modep){
  __shared__ bf16 As[32*264];     // full 32-row x 256-col tile (pad 264; 528B row = 16B-aligned)
  __shared__ bf16 Ws[256*72];
  const int md = *modep;
  int t = threadIdx.x;
  int row0 = blockIdx.x << 5;
  int b = row0 >> 12, l0 = row0 & 4095;
  int lane = t & 63, w = t >> 6, quad = lane >> 4, lr = lane & 15;
  int rg = w & 1, ch2 = w >> 1;
  // stage full tile: 1024 uint4
  #pragma unroll
  for(int pass=0; pass<4; pass++){
    int idx = t + pass*256, r = idx >> 5, ch = idx & 31;
    *(uint4*)&As[r*264 + ch*8] = *(const uint4*)&ymb[((size_t)(row0 + r))*256 + ch*8];
  }
  __syncthreads();
  // LayerNorm: 8 threads per row, 32 cols each
  {
    int row = t >> 3, q = t & 7;
    bf16* rp = As + row*264 + q*32;
    float s = 0.f, s2 = 0.f;
    float vv[32];
    #pragma unroll
    for(int i=0;i<32;i++){ float v = bf2f(rp[i]); vv[i] = v; s += v; s2 += v*v; }
    s  += __shfl_xor(s, 1, 64);  s2 += __shfl_xor(s2, 1, 64);
    s  += __shfl_xor(s, 2, 64);  s2 += __shfl_xor(s2, 2, 64);
    s  += __shfl_xor(s, 4, 64);  s2 += __shfl_xor(s2, 4, 64);
    float mu = s*(1.f/256.f);
    float rs = rsqrtf(s2*(1.f/256.f) - mu*mu + 1e-5f);
    #pragma unroll
    for(int i=0;i<32;i++){
      int cc = q*32 + i;
      rp[i] = f2bf((vv[i]-mu)*rs*ld(gam,cc,md) + ld(bet,cc,md));
    }
  }
  f4_t acc[8];
  #pragma unroll
  for(int nt=0;nt<8;nt++) acc[nt] = (f4_t){0.f,0.f,0.f,0.f};
  for(int kb=0; kb<4; kb++){
    if(kb) __syncthreads();
    int k0 = kb << 6;
    #pragma unroll
    for(int pass=0; pass<8; pass++){
      int idx = t + pass*256, e = idx >> 3, ch = idx & 7;
      *(uint4*)&Ws[e*72 + ch*8] = *(const uint4*)&wb[(size_t)e*256 + k0 + ch*8];
    }
    __syncthreads();
    #pragma unroll
    for(int kk=0; kk<64; kk+=32){
      bf8_t a = *(const bf8_t*)&As[(rg*16 + lr)*264 + k0 + kk + quad*8];
      #pragma unroll
      for(int nt=0;nt<8;nt++){
        bf8_t bb = *(const bf8_t*)&Ws[(ch2*128 + nt*16 + lr)*72 + kk + quad*8];
        acc[nt] = MFMA16(a, bb, acc[nt]);
      }
    }
  }
  __syncthreads();
  bf16* Sl = Ws;   // [256 o][40 l]
  #pragma unroll
  for(int nt=0;nt<8;nt++){
    int o = ch2*128 + nt*16 + lr;
    float bv = ld(pb, (size_t)o, md);
    #pragma unroll
    for(int r=0;r<4;r++)
      Sl[o*40 + rg*16 + quad*4 + r] = f2bf(acc[nt][r] + bv);
  }
  __syncthreads();
  #pragma unroll
  for(int pass=0; pass<4; pass++){
    int idx = t + pass*256, o = idx >> 2, q = idx & 3;
    uint4 v = *(uint4*)&Sl[o*40 + q*8];
    *(uint4*)&outbb[((size_t)(b*256 + o) << 12) + l0 + q*8] = v;
  }
  // fused theta (t<32: one thread per row of this 32-row tile)
  if(t < 32){
    float acc2 = 0.f;
    #pragma unroll 8
    for(int o=0;o<256;o++)
      acc2 = fmaf(bf2f(Sl[o*40 + t]), ld(tw, (size_t)o, md), acc2);
    float v = acc2 + ld(tb2, 0, md);
    theta[((size_t)b << 12) + l0 + t] = 1.f / (1.f + __expf(-v));
  }
}

// ---------------- K9b: depthwise 3x3 + CDC + exact GELU -> gbuf (bf16)
__global__ __launch_bounds__(256) void k_cdc(const bf16* __restrict__ outbb, const float* __restrict__ theta,
                                             const void* __restrict__ cw, bf16* __restrict__ gbufb,
                                             const int* __restrict__ modep){
  const int md = *modep;
  int g = blockIdx.x*256 + threadIdx.x;   // 1,048,576 = 4 b x 256 c x 64 h x 16 w4
  int w4 = g & 15;
  int h0 = (g >> 4) & 63;
  int c  = (g >> 10) & 255;
  int b  = g >> 18;
  int w0 = w4 << 2;
  float wk[9]; float ks = 0.f;
  #pragma unroll
  for(int j=0;j<9;j++){ wk[j] = ld(cw, (size_t)c*9 + j, md); ks += wk[j]; }
  const bf16* base = outbb + (((size_t)b*256 + c) << 12);
  float X[3][6];
  #pragma unroll
  for(int dy=0;dy<3;dy++){
    int hh = h0 + dy - 1;
    #pragma unroll
    for(int dx=0;dx<6;dx++){
      int ww = w0 + dx - 1;
      X[dy][dx] = (hh>=0 && hh<64 && ww>=0 && ww<64) ? bf2f(base[(hh<<6)+ww]) : 0.f;
    }
  }
  float4 th = *(const float4*)&theta[((size_t)b<<12) + (h0<<6) + w0];
  float thv[4] = {th.x, th.y, th.z, th.w};
  __align__(8) bf16 outp[4];
  #pragma unroll
  for(int k=0;k<4;k++){
    float on = 0.f;
    #pragma unroll
    for(int dy=0;dy<3;dy++)
      #pragma unroll
      for(int dx=0;dx<3;dx++)
        on = fmaf(X[dy][k+dx], wk[dy*3+dx], on);
    float ctr  = X[1][k+1];
    float edge = on - ctr*ks;
    float cd   = fmaf(thv[k], edge, on);
    outp[k] = f2bf(0.5f * cd * (1.f + erff(cd * 0.70710678118654752f)));
  }
  *(ushort4*)&gbufb[(((size_t)b*256 + c) << 12) + (h0<<6) + w0] = *(ushort4*)outp;
}

// ---------------- K10: 1x1 pw MFMA + residual, dual-dtype store. 512 blocks.
__global__ __launch_bounds__(256) void k_pw(const bf16* __restrict__ gbufb, const bf16* __restrict__ outbb,
                                            const bf16* __restrict__ wb, void* __restrict__ outp,
                                            const int* __restrict__ modep){
  __shared__ bf16 As[64*72];      // weight tile [64 o][64 c]
  __shared__ bf16 Bs[128*72];     // act tile [128 hw][64 c]
  const int md = *modep;
  int t = threadIdx.x;
  int b  = blockIdx.x >> 7;
  int ot = (blockIdx.x >> 5) & 3;
  int ht = blockIdx.x & 31;
  int o0 = ot << 6, hw0 = ht << 7;
  int lane = t & 63, w = t >> 6, quad = lane >> 4, lr = lane & 15;
  f4_t acc[8];
  #pragma unroll
  for(int nt=0;nt<8;nt++) acc[nt] = (f4_t){0.f,0.f,0.f,0.f};
  for(int kb=0; kb<4; kb++){
    if(kb) __syncthreads();
    int k0 = kb << 6;
    #pragma unroll
    for(int pass=0; pass<2; pass++){
      int idx = t + pass*256, r = idx >> 3, ch = idx & 7;
      *(uint4*)&As[r*72 + ch*8] = *(const uint4*)&wb[(size_t)(o0 + r)*256 + k0 + ch*8];
    }
    #pragma unroll
    for(int pass=0; pass<4; pass++){
      int idx = t + pass*256, cc = idx >> 4, hc = idx & 15;
      uint4 gv = *(const uint4*)&gbufb[((size_t)(b*256 + k0 + cc) << 12) + hw0 + hc*8];
      const bf16* g8 = (const bf16*)&gv;
      #pragma unroll
      for(int j=0;j<8;j++) Bs[(hc*8 + j)*72 + cc] = g8[j];
    }
    __syncthreads();
    #pragma unroll
    for(int kk=0; kk<64; kk+=32){
      bf8_t a = *(const bf8_t*)&As[(w*16 + lr)*72 + kk + quad*8];
      #pragma unroll
      for(int nt=0;nt<8;nt++){
        bf8_t bb = *(const bf8_t*)&Bs[(nt*16 + lr)*72 + kk + quad*8];
        acc[nt] = MFMA16(a, bb, acc[nt]);
      }
    }
  }
  __syncthreads();
  bf16* Sl = Bs;  // [64 o][136 hw]
  #pragma unroll
  for(int nt=0;nt<8;nt++)
    #pragma unroll
    for(int r=0;r<4;r++)
      Sl[(w*16 + quad*4 + r)*136 + nt*16 + lr] = f2bf(acc[nt][r]);
  __syncthreads();
  #pragma unroll
  for(int pass=0; pass<4; pass++){
    int idx = t + pass*256, ol = idx >> 4, c16 = idx & 15;
    size_t ro = ((size_t)(b*256 + o0 + ol) << 12) + hw0 + c16*8;
    uint4 sv = *(uint4*)&Sl[ol*136 + c16*8];
    uint4 rv = *(const uint4*)&outbb[ro];
    const bf16* s8 = (const bf16*)&sv;
    const bf16* r8 = (const bf16*)&rv;
    if(md){
      float4 f0, f1;
      f0.x = bf2f(s8[0]) + bf2f(r8[0]); f0.y = bf2f(s8[1]) + bf2f(r8[1]);
      f0.z = bf2f(s8[2]) + bf2f(r8[2]); f0.w = bf2f(s8[3]) + bf2f(r8[3]);
      f1.x = bf2f(s8[4]) + bf2f(r8[4]); f1.y = bf2f(s8[5]) + bf2f(r8[5]);
      f1.z = bf2f(s8[6]) + bf2f(r8[6]); f1.w = bf2f(s8[7]) + bf2f(r8[7]);
      *(float4*)&((float*)outp)[ro]     = f0;
      *(float4*)&((float*)outp)[ro + 4] = f1;
    } else {
      uint4 ov; bf16* o8 = (bf16*)&ov;
      #pragma unroll
      for(int j=0;j<8;j++) o8[j] = f2bf(bf2f(s8[j]) + bf2f(r8[j]));
      *(uint4*)&((bf16*)outp)[ro] = ov;
    }
  }
}

extern "C" void kernel_launch(void* const* d_in, const int* in_sizes, int n_in,
                              void* d_out, int out_size, void* d_ws, size_t ws_size,
                              hipStream_t stream){
  const void* x      = d_in[0];
  const void* ln_g   = d_in[1];
  const void* ln_b   = d_in[2];
  const void* inw    = d_in[3];
  const void* convw  = d_in[4];
  const void* convb  = d_in[5];
  const void* xpw    = d_in[6];
  const void* dtw    = d_in[7];
  const void* dtb    = d_in[8];
  const void* Alog   = d_in[9];
  const void* Dw     = d_in[10];
  const void* outw   = d_in[11];
  const void* sscale = d_in[12];
  const void* projw  = d_in[13];
  const void* projb  = d_in[14];
  const void* cdcw   = d_in[15];
  const void* thw    = d_in[16];
  const void* thb    = d_in[17];
  const void* pww    = d_in[18];
  float* ws = (float*)d_ws;

  // ---- Workspace layout, f32 SLOT offsets ----
  // [0, 2097152)         xnb  bf16 [4][4096][256]        live ln1..scan3o (skip input)
  // [2097152, 6291456)   xcb  bf16 [16][4096][128]       live inproj..conv
  //    alias             CP   f32  [16][128][128][16]    live cxs1..scan3o (4,194,304 slots exact)
  //    alias [4194304,6291456)  outbb bf16 [4][256][4096] live proj..pw
  // [6291456, 10485760)  zb   bf16 [16][4096][128]       live inproj..scan3o (read-only there)
  //    alias [6291456,8388608)  gbufb bf16 [4][256][4096] live cdc..pw
  // [10485760, 14680064) xsb  bf16 [16][4096][128]       live conv..scan3o
  //    alias             theta f32 [4][4096]             live proj..cdc (written by k_proj)
  // [14680064, 17039360) xdbl f32 [16][4096][36]         live cxs1..scan3o
  // [17039360]           flag int
  // [17039364, 17117188) bf16 weight copies (155648 elems)
  // d_out scratch: CSb bf16[4,194,304] (cxs1..scan2); then ymb bf16 [4][4096][256]
  // (scan3o..proj, RAW pre-LN; LN fused into k_proj); k_pw fully overwrites d_out.
  bf16*  xnb   = (bf16*)(ws);
  bf16*  xcb   = (bf16*)(ws + 2097152);
  float* CP    = ws + 2097152;
  bf16*  outbb = (bf16*)(ws + 4194304);
  bf16*  zb    = (bf16*)(ws + 6291456);
  bf16*  gbufb = (bf16*)(ws + 6291456);
  bf16*  xsb   = (bf16*)(ws + 10485760);
  float* theta = ws + 10485760;
  float* xdbl  = ws + 14680064;
  int*   flag  = (int*)(ws + 17039360);
  bf16*  wsb   = (bf16*)(ws + 17039364);
  bf16*  inwb  = wsb;
  bf16*  outwb = wsb + 16384;
  bf16*  projwb= wsb + 24576;
  bf16*  pwwb  = wsb + 90112;
  bf16*  CSb   = (bf16*)d_out;
  bf16*  ymb   = (bf16*)d_out;

  k_detect <<<1,    256, 0, stream>>>((const unsigned short*)x, flag);
  k_wcvt   <<<608,  256, 0, stream>>>(inw, outw, projw, pww, wsb, flag);
  k_ln1    <<<256,  256, 0, stream>>>(x, ln_g, ln_b, xnb, flag);
  k_inproj <<<1024, 256, 0, stream>>>(xnb, inwb, xcb, zb);
  k_conv   <<<8192, 256, 0, stream>>>(xcb, convw, convb, xsb, flag);
  k_cxs1   <<<1024, 256, 0, stream>>>(xsb, xpw, xdbl, dtw, dtb, Alog, CP, CSb, flag);
  k_scan2  <<<512,  64,  0, stream>>>(CP, CSb);
  k_scan3o <<<2048, 128, 0, stream>>>(zb, xsb, xdbl, dtw, dtb, Alog, Dw, CP,
                                      xnb, outwb, sscale, ymb, flag);
  k_proj   <<<512,  256, 0, stream>>>(ymb, projwb, projb, outbb, ln_g, ln_b,
                                      thw, thb, theta, flag);
  k_cdc    <<<4096, 256, 0, stream>>>(outbb, theta, cdcw, gbufb, flag);
  k_pw     <<<512,  256, 0, stream>>>(gbufb, outbb, pwwb, d_out, flag);
}